// Round 3
// baseline (222.001 us; speedup 1.0000x reference)
//
#include <hip/hip_runtime.h>

namespace {
constexpr int TOK = 8192;
constexpr int DIM = 4096;
constexpr int NE  = 64;
constexpr int TB  = 128;          // tokens per gemm tile (8 waves x 16)
constexpr int KS  = 8;            // split-K factor
constexpr int KR  = DIM / KS;     // 512 k per block
constexpr int NKS = KR / 32;      // 16 K32-steps per block
constexpr int TOTKS = DIM / 32;   // 128 K32-steps total
constexpr int NT  = TOK / TB;     // 64 token tiles
constexpr int GB  = 64;           // tokens per gating chunk
constexpr int NCH = TOK / GB;     // 128 chunks
}

typedef _Float16 f16x8 __attribute__((ext_vector_type(8)));
typedef float    f32x4 __attribute__((ext_vector_type(4)));

// ---------------------------------------------------------------------------
// Pre-pack W (fp32 [64][4096]) into MFMA B-fragment order, fp16 hi/lo:
// packed[(et*TOTKS + gk)*64 + lane] = W[et*16 + (lane&15)][gk*32 + (lane>>4)*8 ..+8]
// ---------------------------------------------------------------------------
__global__ __launch_bounds__(256) void prepack_w(
    const float* __restrict__ W, f16x8* __restrict__ whi,
    f16x8* __restrict__ wlo) {
  const int gid = blockIdx.x * 256 + threadIdx.x;   // [0, 4*128*64)
  const int lane = gid & 63;
  const int gk   = (gid >> 6) & (TOTKS - 1);
  const int et   = gid >> 13;
  const int e = et * 16 + (lane & 15);
  const int k = gk * 32 + (lane >> 4) * 8;
  const float4 r0 = *(const float4*)(W + (size_t)e * DIM + k);
  const float4 r1 = *(const float4*)(W + (size_t)e * DIM + k + 4);
  f16x8 hi, lo;
  const float rv[8] = {r0.x, r0.y, r0.z, r0.w, r1.x, r1.y, r1.z, r1.w};
#pragma unroll
  for (int j = 0; j < 8; ++j) {
    const _Float16 h = (_Float16)rv[j];
    hi[j] = h;
    lo[j] = (_Float16)(rv[j] - (float)h);
  }
  whi[gid] = hi;
  wlo[gid] = lo;
}

// ---------------------------------------------------------------------------
// Split-K GEMM, zero LDS. 512 blocks x 512 threads. Wave w owns tokens
// [t0 + w*16, +16) x all 64 experts (4 et-tiles). A loaded fp32 from global
// (lane-private rows, K-contiguous), split to fp16 hi/lo in registers;
// B fragments loaded pre-packed (coalesced, L2-resident).
// logits ~= Ahi*Bhi + Ahi*Blo + Alo*Bhi   (fp16x2 split, ~22-bit mantissa)
// ---------------------------------------------------------------------------
__global__ __launch_bounds__(512, 4) void gemm_split(
    const float* __restrict__ A, const f16x8* __restrict__ whi,
    const f16x8* __restrict__ wlo, float* __restrict__ partial) {
  const int bid  = blockIdx.x;
  const int tile = bid & (NT - 1);
  const int ks   = bid / NT;
  const int t0   = tile * TB;
  const int tid  = threadIdx.x;
  const int w    = tid >> 6;        // wave 0..7
  const int lane = tid & 63;
  const int col  = lane & 15;
  const int quad = lane >> 4;

  // this lane's A row pointer: token t0 + w*16 + col, k = ks*KR + quad*8
  const float* Ap = A + (size_t)(t0 + w * 16 + col) * DIM + ks * KR + quad * 8;
  const int gk0 = ks * NKS;

  f32x4 acc[4];
#pragma unroll
  for (int et = 0; et < 4; ++et) acc[et] = (f32x4)0.0f;

  float4 a0 = *(const float4*)(Ap);
  float4 a1 = *(const float4*)(Ap + 4);

  for (int it = 0; it < NKS; ++it) {
    // B fragments for this k-step (L2-hit, coalesced)
    f16x8 bh[4], bl[4];
#pragma unroll
    for (int et = 0; et < 4; ++et) {
      const size_t bi = ((size_t)(et * TOTKS + gk0 + it) << 6) + lane;
      bh[et] = whi[bi];
      bl[et] = wlo[bi];
    }
    // prefetch next A chunk
    float4 a0n, a1n;
    if (it + 1 < NKS) {
      a0n = *(const float4*)(Ap + (it + 1) * 32);
      a1n = *(const float4*)(Ap + (it + 1) * 32 + 4);
    }
    // convert A fp32 -> fp16 hi/lo in registers
    const float av[8] = {a0.x, a0.y, a0.z, a0.w, a1.x, a1.y, a1.z, a1.w};
    f16x8 ah, al;
#pragma unroll
    for (int j = 0; j < 8; ++j) {
      const _Float16 h = (_Float16)av[j];
      ah[j] = h;
      al[j] = (_Float16)(av[j] - (float)h);
    }
#pragma unroll
    for (int et = 0; et < 4; ++et) {
      acc[et] = __builtin_amdgcn_mfma_f32_16x16x32_f16(ah, bh[et], acc[et], 0, 0, 0);
      acc[et] = __builtin_amdgcn_mfma_f32_16x16x32_f16(ah, bl[et], acc[et], 0, 0, 0);
      acc[et] = __builtin_amdgcn_mfma_f32_16x16x32_f16(al, bh[et], acc[et], 0, 0, 0);
    }
    a0 = a0n; a1 = a1n;
  }

  // epilogue: C/D col=lane&15 (expert low), row=quad*4+r (token)
  float* P = partial + (size_t)ks * TOK * NE;
  const int tb = t0 + w * 16 + quad * 4;
#pragma unroll
  for (int et = 0; et < 4; ++et) {
    const int e = et * 16 + col;
#pragma unroll
    for (int r = 0; r < 4; ++r)
      P[(size_t)(tb + r) * NE + e] = acc[et][r];
  }
}

// ---------------------------------------------------------------------------
// Gating: sum split-K partials -> logits; argmax / softmax / per-chunk rank +
// histogram; me partials per block (no atomics).
// ---------------------------------------------------------------------------
__global__ __launch_bounds__(256) void gating(
    const float* __restrict__ partial, float* __restrict__ out,
    int* __restrict__ idx_int, int* __restrict__ rankp,
    int* __restrict__ hist, float* __restrict__ me_part) {
  __shared__ float L[GB * 65];     // 64 tokens x 64 logits, stride 65
  __shared__ float mx[GB];
  __shared__ float dninv[GB];
  __shared__ int   eid[GB];
  const int b = blockIdx.x, tid = threadIdx.x;
  const size_t base = (size_t)b * GB * NE;

#pragma unroll
  for (int j = 0; j < (GB * NE) / 256; ++j) {   // 16 elements / thread
    const int idx = tid + 256 * j;
    float s = 0.0f;
#pragma unroll
    for (int k = 0; k < KS; ++k)
      s += partial[(size_t)k * TOK * NE + base + idx];
    L[(idx >> 6) * 65 + (idx & 63)] = s;
  }
  __syncthreads();

  if (tid < GB) {  // one thread per token: argmax (first-occurrence) + softmax
    const int t = tid;
    float m = -3.0e38f; int bi = 0;
    for (int e = 0; e < NE; ++e) {
      const float v = L[t * 65 + e];
      if (v > m) { m = v; bi = e; }
    }
    float s = 0.0f;
    for (int e = 0; e < NE; ++e) s += __expf(L[t * 65 + e] - m);
    const float inv = 1.0f / s;
    mx[t] = m; dninv[t] = inv; eid[t] = bi;
    const int gt = b * GB + t;
    out[1 + gt]           = (float)bi;   // indices1_s
    out[1 + 2 * TOK + gt] = inv;         // gates1_s
    idx_int[gt] = bi;
  }
  __syncthreads();

  if (tid < GB) {  // within-chunk rank + chunk histogram
    const int t = tid, e = eid[t];
    int r = 0;
    for (int j = 0; j < t; ++j) r += (eid[j] == e) ? 1 : 0;
    rankp[b * GB + t] = r;
    int c = 0;
    for (int t2 = 0; t2 < GB; ++t2) c += (eid[t2] == tid) ? 1 : 0;
    hist[b * NE + tid] = c;
  } else if (tid < 2 * GB) {  // wave 1: me[e] partial sum for this chunk
    const int e = tid - GB;
    float s = 0.0f;
    for (int t2 = 0; t2 < GB; ++t2)
      s += __expf(L[t2 * 65 + e] - mx[t2]) * dninv[t2];
    me_part[b * NE + e] = s;
  }
}

// ---------------------------------------------------------------------------
// Finalize: segmented per-expert exclusive scan over chunk hists -> locations;
// ce + me reduce -> l_aux.
// ---------------------------------------------------------------------------
__global__ __launch_bounds__(256) void finalize(
    const int* __restrict__ idx_int, const int* __restrict__ rankp,
    const int* __restrict__ hist, const float* __restrict__ me_part,
    float* __restrict__ out) {
  __shared__ int   H[NCH * NE];    // 32 KB
  __shared__ int   SEG[4 * NE];
  __shared__ float MEp[4 * NE];
  __shared__ float CE[NE];
  const int tid = threadIdx.x;
  const int e = tid & 63, seg = tid >> 6;   // 4 segments x 32 chunks

  for (int j = tid; j < NCH * NE; j += 256) H[j] = hist[j];
  {
    float s = 0.0f;
    for (int c = seg * 32; c < seg * 32 + 32; ++c) s += me_part[c * NE + e];
    MEp[seg * NE + e] = s;
  }
  __syncthreads();
  {
    int hs = 0;
    for (int c = seg * 32; c < seg * 32 + 32; ++c) hs += H[c * NE + e];
    SEG[seg * NE + e] = hs;
  }
  __syncthreads();
  if (tid < NE) {  // exclusive scan of 4 segment sums per expert
    int run = 0;
    for (int s2 = 0; s2 < 4; ++s2) {
      const int v = SEG[s2 * NE + tid];
      SEG[s2 * NE + tid] = run;
      run += v;
    }
    CE[tid] = (float)run;  // ce[e]
  }
  __syncthreads();
  {  // per (e,seg): exclusive scan within segment
    int run = SEG[seg * NE + e];
    for (int c = seg * 32; c < seg * 32 + 32; ++c) {
      const int v = H[c * NE + e];
      H[c * NE + e] = run;
      run += v;
    }
  }
  if (tid < 64) {  // l_aux
    float p = (MEp[tid] + MEp[NE + tid] + MEp[2 * NE + tid] + MEp[3 * NE + tid])
              * CE[tid];
#pragma unroll
    for (int off = 32; off > 0; off >>= 1) p += __shfl_down(p, off);
    if (tid == 0) out[0] = p * ((float)NE / ((float)TOK * (float)TOK));
  }
  __syncthreads();
#pragma unroll 4
  for (int i = tid; i < TOK; i += 256) {  // locations1_s
    const int ex = idx_int[i];
    out[1 + TOK + i] = (float)(H[(i >> 6) * NE + ex] + rankp[i]);
  }
}

extern "C" void kernel_launch(void* const* d_in, const int* in_sizes, int n_in,
                              void* d_out, int out_size, void* d_ws, size_t ws_size,
                              hipStream_t stream) {
  const float* A = (const float*)d_in[0];   // [8192, 4096] fp32
  const float* W = (const float*)d_in[1];   // [64, 4096] fp32
  float* out = (float*)d_out;               // 1 + 8192*3 floats
  char* ws = (char*)d_ws;

  float* partial = (float*)ws;                                  // 16 MB
  size_t off = (size_t)KS * TOK * NE * sizeof(float);
  f16x8* whi = (f16x8*)(ws + off);  off += (size_t)4 * TOTKS * 64 * 16;  // 512 KB
  f16x8* wlo = (f16x8*)(ws + off);  off += (size_t)4 * TOTKS * 64 * 16;  // 512 KB
  float* me_part = (float*)(ws + off);  off += (size_t)NCH * NE * sizeof(float);
  int* idx_int = (int*)(ws + off);      off += (size_t)TOK * sizeof(int);
  int* rankp   = (int*)(ws + off);      off += (size_t)TOK * sizeof(int);
  int* hist    = (int*)(ws + off);

  hipLaunchKernelGGL(prepack_w, dim3(128), dim3(256), 0, stream, W, whi, wlo);
  hipLaunchKernelGGL(gemm_split, dim3(NT * KS), dim3(512), 0, stream,
                     A, whi, wlo, partial);
  hipLaunchKernelGGL(gating, dim3(NCH), dim3(256), 0, stream, partial, out,
                     idx_int, rankp, hist, me_part);
  hipLaunchKernelGGL(finalize, dim3(1), dim3(256), 0, stream, idx_int, rankp,
                     hist, me_part, out);
}

// Round 4
// 220.438 us; speedup vs baseline: 1.0071x; 1.0071x over previous
//
#include <hip/hip_runtime.h>

namespace {
constexpr int TOK = 8192;
constexpr int DIM = 4096;
constexpr int NE  = 64;
constexpr int TB  = 128;          // tokens per gemm tile (8 waves x 16)
constexpr int KS  = 8;            // split-K factor
constexpr int KR  = DIM / KS;     // 512 k per block
constexpr int NKS = KR / 32;      // 16 K32-steps per block
constexpr int TOTKS = DIM / 32;   // 128 K32-steps total
constexpr int NT  = TOK / TB;     // 64 token tiles
constexpr int GB  = 64;           // tokens per gating chunk
constexpr int NCH = TOK / GB;     // 128 chunks
}

typedef _Float16 f16x8 __attribute__((ext_vector_type(8)));
typedef float    f32x4 __attribute__((ext_vector_type(4)));

// ---------------------------------------------------------------------------
// Pre-pack W (fp32 [64][4096]) into MFMA B-fragment order, fp16 hi/lo:
// packed[(et*TOTKS + gk)*64 + lane] = W[et*16 + (lane&15)][gk*32 + (lane>>4)*8 ..+8]
// ---------------------------------------------------------------------------
__global__ __launch_bounds__(256) void prepack_w(
    const float* __restrict__ W, f16x8* __restrict__ whi,
    f16x8* __restrict__ wlo) {
  const int gid = blockIdx.x * 256 + threadIdx.x;   // [0, 4*128*64)
  const int lane = gid & 63;
  const int gk   = (gid >> 6) & (TOTKS - 1);
  const int et   = gid >> 13;
  const int e = et * 16 + (lane & 15);
  const int k = gk * 32 + (lane >> 4) * 8;
  const float4 r0 = *(const float4*)(W + (size_t)e * DIM + k);
  const float4 r1 = *(const float4*)(W + (size_t)e * DIM + k + 4);
  f16x8 hi, lo;
  const float rv[8] = {r0.x, r0.y, r0.z, r0.w, r1.x, r1.y, r1.z, r1.w};
#pragma unroll
  for (int j = 0; j < 8; ++j) {
    const _Float16 h = (_Float16)rv[j];
    hi[j] = h;
    lo[j] = (_Float16)(rv[j] - (float)h);
  }
  whi[gid] = hi;
  wlo[gid] = lo;
}

// ---------------------------------------------------------------------------
// Split-K GEMM, zero LDS, register software pipeline: B depth 1, A depth 2.
// 512 blocks x 512 threads. Wave w owns tokens [t0+w*16, +16) x 64 experts.
// logits ~= Ahi*Bhi + Ahi*Blo + Alo*Bhi   (fp16x2 split, ~22-bit mantissa)
// ---------------------------------------------------------------------------
__global__ __launch_bounds__(512, 4) void gemm_split(
    const float* __restrict__ A, const f16x8* __restrict__ whi,
    const f16x8* __restrict__ wlo, float* __restrict__ partial) {
  const int bid  = blockIdx.x;
  const int tile = bid & (NT - 1);
  const int ks   = bid / NT;
  const int t0   = tile * TB;
  const int tid  = threadIdx.x;
  const int w    = tid >> 6;        // wave 0..7
  const int lane = tid & 63;
  const int col  = lane & 15;
  const int quad = lane >> 4;

  // this lane's A row: token t0 + w*16 + col, k = ks*KR + quad*8
  const float* Ap = A + (size_t)(t0 + w * 16 + col) * DIM + ks * KR + quad * 8;
  const int gk0 = ks * NKS;

  f32x4 acc[4];
#pragma unroll
  for (int et = 0; et < 4; ++et) acc[et] = (f32x4)0.0f;

  // pipeline prologue: A(0), A(1), B(0)
  float4 a0  = *(const float4*)(Ap);
  float4 a1  = *(const float4*)(Ap + 4);
  float4 a0n = *(const float4*)(Ap + 32);
  float4 a1n = *(const float4*)(Ap + 36);
  f16x8 bh[4], bl[4];
#pragma unroll
  for (int et = 0; et < 4; ++et) {
    const size_t bi = ((size_t)(et * TOTKS + gk0) << 6) + lane;
    bh[et] = whi[bi];
    bl[et] = wlo[bi];
  }

  for (int it = 0; it < NKS; ++it) {
    // issue next-step loads first (in flight across this step's MFMA)
    f16x8 bhn[4], bln[4];
    if (it + 1 < NKS) {
#pragma unroll
      for (int et = 0; et < 4; ++et) {
        const size_t bi = ((size_t)(et * TOTKS + gk0 + it + 1) << 6) + lane;
        bhn[et] = whi[bi];
        bln[et] = wlo[bi];
      }
    }
    float4 a0nn, a1nn;
    if (it + 2 < NKS) {
      a0nn = *(const float4*)(Ap + (it + 2) * 32);
      a1nn = *(const float4*)(Ap + (it + 2) * 32 + 4);
    }
    // convert A fp32 -> fp16 hi/lo in registers
    const float av[8] = {a0.x, a0.y, a0.z, a0.w, a1.x, a1.y, a1.z, a1.w};
    f16x8 ah, al;
#pragma unroll
    for (int j = 0; j < 8; ++j) {
      const _Float16 h = (_Float16)av[j];
      ah[j] = h;
      al[j] = (_Float16)(av[j] - (float)h);
    }
#pragma unroll
    for (int et = 0; et < 4; ++et) {
      acc[et] = __builtin_amdgcn_mfma_f32_16x16x32_f16(ah, bh[et], acc[et], 0, 0, 0);
      acc[et] = __builtin_amdgcn_mfma_f32_16x16x32_f16(ah, bl[et], acc[et], 0, 0, 0);
      acc[et] = __builtin_amdgcn_mfma_f32_16x16x32_f16(al, bh[et], acc[et], 0, 0, 0);
    }
    // rotate pipeline registers
    a0 = a0n; a1 = a1n; a0n = a0nn; a1n = a1nn;
#pragma unroll
    for (int et = 0; et < 4; ++et) { bh[et] = bhn[et]; bl[et] = bln[et]; }
  }

  // epilogue: C/D col=lane&15 (expert low), row=quad*4+r (token)
  float* P = partial + (size_t)ks * TOK * NE;
  const int tb = t0 + w * 16 + quad * 4;
#pragma unroll
  for (int et = 0; et < 4; ++et) {
    const int e = et * 16 + col;
#pragma unroll
    for (int r = 0; r < 4; ++r)
      P[(size_t)(tb + r) * NE + e] = acc[et][r];
  }
}

// ---------------------------------------------------------------------------
// Gating: sum split-K partials -> logits; argmax / softmax / per-chunk rank +
// histogram; me partials per block (no atomics).
// ---------------------------------------------------------------------------
__global__ __launch_bounds__(256) void gating(
    const float* __restrict__ partial, float* __restrict__ out,
    int* __restrict__ idx_int, int* __restrict__ rankp,
    int* __restrict__ hist, float* __restrict__ me_part) {
  __shared__ float L[GB * 65];     // 64 tokens x 64 logits, stride 65
  __shared__ float mx[GB];
  __shared__ float dninv[GB];
  __shared__ int   eid[GB];
  const int b = blockIdx.x, tid = threadIdx.x;
  const size_t base = (size_t)b * GB * NE;

#pragma unroll
  for (int j = 0; j < (GB * NE) / 256; ++j) {   // 16 elements / thread
    const int idx = tid + 256 * j;
    float s = 0.0f;
#pragma unroll
    for (int k = 0; k < KS; ++k)
      s += partial[(size_t)k * TOK * NE + base + idx];
    L[(idx >> 6) * 65 + (idx & 63)] = s;
  }
  __syncthreads();

  if (tid < GB) {  // one thread per token: argmax (first-occurrence) + softmax
    const int t = tid;
    float m = -3.0e38f; int bi = 0;
    for (int e = 0; e < NE; ++e) {
      const float v = L[t * 65 + e];
      if (v > m) { m = v; bi = e; }
    }
    float s = 0.0f;
    for (int e = 0; e < NE; ++e) s += __expf(L[t * 65 + e] - m);
    const float inv = 1.0f / s;
    mx[t] = m; dninv[t] = inv; eid[t] = bi;
    const int gt = b * GB + t;
    out[1 + gt]           = (float)bi;   // indices1_s
    out[1 + 2 * TOK + gt] = inv;         // gates1_s
    idx_int[gt] = bi;
  }
  __syncthreads();

  if (tid < GB) {  // within-chunk rank + chunk histogram
    const int t = tid, e = eid[t];
    int r = 0;
    for (int j = 0; j < t; ++j) r += (eid[j] == e) ? 1 : 0;
    rankp[b * GB + t] = r;
    int c = 0;
    for (int t2 = 0; t2 < GB; ++t2) c += (eid[t2] == tid) ? 1 : 0;
    hist[b * NE + tid] = c;
  } else if (tid < 2 * GB) {  // wave 1: me[e] partial sum for this chunk
    const int e = tid - GB;
    float s = 0.0f;
    for (int t2 = 0; t2 < GB; ++t2)
      s += __expf(L[t2 * 65 + e] - mx[t2]) * dninv[t2];
    me_part[b * NE + e] = s;
  }
}

// ---------------------------------------------------------------------------
// Finalize: segmented per-expert exclusive scan over chunk hists -> locations;
// ce + me reduce -> l_aux.
// ---------------------------------------------------------------------------
__global__ __launch_bounds__(256) void finalize(
    const int* __restrict__ idx_int, const int* __restrict__ rankp,
    const int* __restrict__ hist, const float* __restrict__ me_part,
    float* __restrict__ out) {
  __shared__ int   H[NCH * NE];    // 32 KB
  __shared__ int   SEG[4 * NE];
  __shared__ float MEp[4 * NE];
  __shared__ float CE[NE];
  const int tid = threadIdx.x;
  const int e = tid & 63, seg = tid >> 6;   // 4 segments x 32 chunks

  for (int j = tid; j < NCH * NE; j += 256) H[j] = hist[j];
  {
    float s = 0.0f;
    for (int c = seg * 32; c < seg * 32 + 32; ++c) s += me_part[c * NE + e];
    MEp[seg * NE + e] = s;
  }
  __syncthreads();
  {
    int hs = 0;
    for (int c = seg * 32; c < seg * 32 + 32; ++c) hs += H[c * NE + e];
    SEG[seg * NE + e] = hs;
  }
  __syncthreads();
  if (tid < NE) {  // exclusive scan of 4 segment sums per expert
    int run = 0;
    for (int s2 = 0; s2 < 4; ++s2) {
      const int v = SEG[s2 * NE + tid];
      SEG[s2 * NE + tid] = run;
      run += v;
    }
    CE[tid] = (float)run;  // ce[e]
  }
  __syncthreads();
  {  // per (e,seg): exclusive scan within segment
    int run = SEG[seg * NE + e];
    for (int c = seg * 32; c < seg * 32 + 32; ++c) {
      const int v = H[c * NE + e];
      H[c * NE + e] = run;
      run += v;
    }
  }
  if (tid < 64) {  // l_aux
    float p = (MEp[tid] + MEp[NE + tid] + MEp[2 * NE + tid] + MEp[3 * NE + tid])
              * CE[tid];
#pragma unroll
    for (int off = 32; off > 0; off >>= 1) p += __shfl_down(p, off);
    if (tid == 0) out[0] = p * ((float)NE / ((float)TOK * (float)TOK));
  }
  __syncthreads();
#pragma unroll 4
  for (int i = tid; i < TOK; i += 256) {  // locations1_s
    const int ex = idx_int[i];
    out[1 + TOK + i] = (float)(H[(i >> 6) * NE + ex] + rankp[i]);
  }
}

extern "C" void kernel_launch(void* const* d_in, const int* in_sizes, int n_in,
                              void* d_out, int out_size, void* d_ws, size_t ws_size,
                              hipStream_t stream) {
  const float* A = (const float*)d_in[0];   // [8192, 4096] fp32
  const float* W = (const float*)d_in[1];   // [64, 4096] fp32
  float* out = (float*)d_out;               // 1 + 8192*3 floats
  char* ws = (char*)d_ws;

  float* partial = (float*)ws;                                  // 16 MB
  size_t off = (size_t)KS * TOK * NE * sizeof(float);
  f16x8* whi = (f16x8*)(ws + off);  off += (size_t)4 * TOTKS * 64 * 16;  // 512 KB
  f16x8* wlo = (f16x8*)(ws + off);  off += (size_t)4 * TOTKS * 64 * 16;  // 512 KB
  float* me_part = (float*)(ws + off);  off += (size_t)NCH * NE * sizeof(float);
  int* idx_int = (int*)(ws + off);      off += (size_t)TOK * sizeof(int);
  int* rankp   = (int*)(ws + off);      off += (size_t)TOK * sizeof(int);
  int* hist    = (int*)(ws + off);

  hipLaunchKernelGGL(prepack_w, dim3(128), dim3(256), 0, stream, W, whi, wlo);
  hipLaunchKernelGGL(gemm_split, dim3(NT * KS), dim3(512), 0, stream,
                     A, whi, wlo, partial);
  hipLaunchKernelGGL(gating, dim3(NCH), dim3(256), 0, stream, partial, out,
                     idx_int, rankp, hist, me_part);
  hipLaunchKernelGGL(finalize, dim3(1), dim3(256), 0, stream, idx_int, rankp,
                     hist, me_part, out);
}

// Round 5
// 214.289 us; speedup vs baseline: 1.0360x; 1.0287x over previous
//
#include <hip/hip_runtime.h>

namespace {
constexpr int TOK = 8192;
constexpr int DIM = 4096;
constexpr int NE  = 64;
constexpr int TB  = 128;          // tokens per gemm tile (8 waves x 16)
constexpr int KS  = 8;            // split-K factor
constexpr int KR  = DIM / KS;     // 512 k per block
constexpr int NKS = KR / 32;      // 16 K32-steps per block
constexpr int TOTKS = DIM / 32;   // 128 K32-steps total
constexpr int NT  = TOK / TB;     // 64 token tiles
constexpr int GB  = 64;           // tokens per gating chunk
constexpr int NCH = TOK / GB;     // 128 chunks
}

typedef _Float16 f16x8 __attribute__((ext_vector_type(8)));
typedef float    f32x4 __attribute__((ext_vector_type(4)));

// ---------------------------------------------------------------------------
// Pre-pack W (fp32 [64][4096]) into MFMA B-fragment order, fp16 hi/lo:
// packed[(et*TOTKS + gk)*64 + lane] = W[et*16 + (lane&15)][gk*32 + (lane>>4)*8 ..+8]
// ---------------------------------------------------------------------------
__global__ __launch_bounds__(256) void prepack_w(
    const float* __restrict__ W, f16x8* __restrict__ whi,
    f16x8* __restrict__ wlo) {
  const int gid = blockIdx.x * 256 + threadIdx.x;   // [0, 4*128*64)
  const int lane = gid & 63;
  const int gk   = (gid >> 6) & (TOTKS - 1);
  const int et   = gid >> 13;
  const int e = et * 16 + (lane & 15);
  const int k = gk * 32 + (lane >> 4) * 8;
  const float4 r0 = *(const float4*)(W + (size_t)e * DIM + k);
  const float4 r1 = *(const float4*)(W + (size_t)e * DIM + k + 4);
  f16x8 hi, lo;
  const float rv[8] = {r0.x, r0.y, r0.z, r0.w, r1.x, r1.y, r1.z, r1.w};
#pragma unroll
  for (int j = 0; j < 8; ++j) {
    const _Float16 h = (_Float16)rv[j];
    hi[j] = h;
    lo[j] = (_Float16)(rv[j] - (float)h);
  }
  whi[gid] = hi;
  wlo[gid] = lo;
}

// ---------------------------------------------------------------------------
// Split-K GEMM. B hi/lo slice staged into LDS once per half-K via
// global_load_lds (structural latency hiding, zero pipeline VGPRs); A streamed
// from global with a depth-2 register pipeline. 512 blocks x 512 threads,
// 64 KB LDS -> 2 blocks/CU, 4 waves/SIMD.
// logits ~= Ahi*Bhi + Ahi*Blo + Alo*Bhi   (fp16x2 split, ~22-bit mantissa)
// ---------------------------------------------------------------------------
__global__ __launch_bounds__(512, 4) void gemm_split(
    const float* __restrict__ A, const _Float16* __restrict__ whi,
    const _Float16* __restrict__ wlo, float* __restrict__ partial) {
  // 8 chunks (fmt*4+et) x 8 steps x 64 lanes x 8 halves = 64 KB
  __shared__ _Float16 sB[8 * 8 * 64 * 8];

  const int bid  = blockIdx.x;
  const int tile = bid & (NT - 1);
  const int ks   = bid / NT;
  const int t0   = tile * TB;
  const int tid  = threadIdx.x;
  const int w    = tid >> 6;        // wave 0..7
  const int lane = tid & 63;
  const int col  = lane & 15;
  const int quad = lane >> 4;
  const int gk0  = ks * NKS;

  // this lane's A row: token t0 + w*16 + col, k = ks*KR + quad*8
  const float* Ap = A + (size_t)(t0 + w * 16 + col) * DIM + ks * KR + quad * 8;

  f32x4 acc[4];
#pragma unroll
  for (int et = 0; et < 4; ++et) acc[et] = (f32x4)0.0f;

  // A pipeline prologue: steps 0 and 1 in flight
  float4 a0  = *(const float4*)(Ap);
  float4 a1  = *(const float4*)(Ap + 4);
  float4 a0n = *(const float4*)(Ap + 32);
  float4 a1n = *(const float4*)(Ap + 36);

  // wave w stages chunk w: fmt = w>>2 (0=hi,1=lo), et = w&3
  const _Float16* src_base =
      ((w < 4) ? whi : wlo) + ((size_t)((w & 3) * TOTKS + gk0) << 9);
  _Float16* dst_base = sB + ((size_t)w << 12);  // w * 8 steps * 512 halves

  for (int half = 0; half < 2; ++half) {
    if (half) __syncthreads();   // all reads of the buffer done
    // stage 8 steps x 1 KB for this wave's chunk
#pragma unroll
    for (int i = 0; i < 8; ++i) {
      const _Float16* src = src_base + (((size_t)(half * 8 + i)) << 9) + lane * 8;
      _Float16* dst = dst_base + ((size_t)i << 9) + lane * 8;
      __builtin_amdgcn_global_load_lds(
          (const __attribute__((address_space(1))) void*)src,
          (__attribute__((address_space(3))) void*)dst, 16, 0, 0);
    }
    __syncthreads();             // staging complete (vmcnt drained by barrier)

    for (int s = 0; s < 8; ++s) {
      const int it = half * 8 + s;
      // issue A(it+2)
      float4 a0nn, a1nn;
      if (it + 2 < NKS) {
        a0nn = *(const float4*)(Ap + (it + 2) * 32);
        a1nn = *(const float4*)(Ap + (it + 2) * 32 + 4);
      }
      // convert A fp32 -> fp16 hi/lo in registers
      const float av[8] = {a0.x, a0.y, a0.z, a0.w, a1.x, a1.y, a1.z, a1.w};
      f16x8 ah, al;
#pragma unroll
      for (int j = 0; j < 8; ++j) {
        const _Float16 h = (_Float16)av[j];
        ah[j] = h;
        al[j] = (_Float16)(av[j] - (float)h);
      }
#pragma unroll
      for (int et = 0; et < 4; ++et) {
        const f16x8 bh = *(const f16x8*)(sB + ((et * 8 + s) << 9) + lane * 8);
        const f16x8 bl =
            *(const f16x8*)(sB + (((4 + et) * 8 + s) << 9) + lane * 8);
        acc[et] = __builtin_amdgcn_mfma_f32_16x16x32_f16(ah, bh, acc[et], 0, 0, 0);
        acc[et] = __builtin_amdgcn_mfma_f32_16x16x32_f16(ah, bl, acc[et], 0, 0, 0);
        acc[et] = __builtin_amdgcn_mfma_f32_16x16x32_f16(al, bh, acc[et], 0, 0, 0);
      }
      a0 = a0n; a1 = a1n; a0n = a0nn; a1n = a1nn;
    }
  }

  // epilogue: C/D col=lane&15 (expert low), row=quad*4+r (token)
  float* P = partial + (size_t)ks * TOK * NE;
  const int tb = t0 + w * 16 + quad * 4;
#pragma unroll
  for (int et = 0; et < 4; ++et) {
    const int e = et * 16 + col;
#pragma unroll
    for (int r = 0; r < 4; ++r)
      P[(size_t)(tb + r) * NE + e] = acc[et][r];
  }
}

// ---------------------------------------------------------------------------
// Gating: sum split-K partials -> logits; argmax / softmax / per-chunk rank +
// histogram; me partials per block (no atomics).
// ---------------------------------------------------------------------------
__global__ __launch_bounds__(256) void gating(
    const float* __restrict__ partial, float* __restrict__ out,
    int* __restrict__ idx_int, int* __restrict__ rankp,
    int* __restrict__ hist, float* __restrict__ me_part) {
  __shared__ float L[GB * 65];     // 64 tokens x 64 logits, stride 65
  __shared__ float mx[GB];
  __shared__ float dninv[GB];
  __shared__ int   eid[GB];
  const int b = blockIdx.x, tid = threadIdx.x;
  const size_t base = (size_t)b * GB * NE;

#pragma unroll
  for (int j = 0; j < (GB * NE) / 256; ++j) {   // 16 elements / thread
    const int idx = tid + 256 * j;
    float s = 0.0f;
#pragma unroll
    for (int k = 0; k < KS; ++k)
      s += partial[(size_t)k * TOK * NE + base + idx];
    L[(idx >> 6) * 65 + (idx & 63)] = s;
  }
  __syncthreads();

  if (tid < GB) {  // one thread per token: argmax (first-occurrence) + softmax
    const int t = tid;
    float m = -3.0e38f; int bi = 0;
    for (int e = 0; e < NE; ++e) {
      const float v = L[t * 65 + e];
      if (v > m) { m = v; bi = e; }
    }
    float s = 0.0f;
    for (int e = 0; e < NE; ++e) s += __expf(L[t * 65 + e] - m);
    const float inv = 1.0f / s;
    mx[t] = m; dninv[t] = inv; eid[t] = bi;
    const int gt = b * GB + t;
    out[1 + gt]           = (float)bi;   // indices1_s
    out[1 + 2 * TOK + gt] = inv;         // gates1_s
    idx_int[gt] = bi;
  }
  __syncthreads();

  if (tid < GB) {  // within-chunk rank + chunk histogram
    const int t = tid, e = eid[t];
    int r = 0;
    for (int j = 0; j < t; ++j) r += (eid[j] == e) ? 1 : 0;
    rankp[b * GB + t] = r;
    int c = 0;
    for (int t2 = 0; t2 < GB; ++t2) c += (eid[t2] == tid) ? 1 : 0;
    hist[b * NE + tid] = c;
  } else if (tid < 2 * GB) {  // wave 1: me[e] partial sum for this chunk
    const int e = tid - GB;
    float s = 0.0f;
    for (int t2 = 0; t2 < GB; ++t2)
      s += __expf(L[t2 * 65 + e] - mx[t2]) * dninv[t2];
    me_part[b * NE + e] = s;
  }
}

// ---------------------------------------------------------------------------
// Finalize: segmented per-expert exclusive scan over chunk hists -> locations;
// ce + me reduce -> l_aux.
// ---------------------------------------------------------------------------
__global__ __launch_bounds__(256) void finalize(
    const int* __restrict__ idx_int, const int* __restrict__ rankp,
    const int* __restrict__ hist, const float* __restrict__ me_part,
    float* __restrict__ out) {
  __shared__ int   H[NCH * NE];    // 32 KB
  __shared__ int   SEG[4 * NE];
  __shared__ float MEp[4 * NE];
  __shared__ float CE[NE];
  const int tid = threadIdx.x;
  const int e = tid & 63, seg = tid >> 6;   // 4 segments x 32 chunks

  for (int j = tid; j < NCH * NE; j += 256) H[j] = hist[j];
  {
    float s = 0.0f;
    for (int c = seg * 32; c < seg * 32 + 32; ++c) s += me_part[c * NE + e];
    MEp[seg * NE + e] = s;
  }
  __syncthreads();
  {
    int hs = 0;
    for (int c = seg * 32; c < seg * 32 + 32; ++c) hs += H[c * NE + e];
    SEG[seg * NE + e] = hs;
  }
  __syncthreads();
  if (tid < NE) {  // exclusive scan of 4 segment sums per expert
    int run = 0;
    for (int s2 = 0; s2 < 4; ++s2) {
      const int v = SEG[s2 * NE + tid];
      SEG[s2 * NE + tid] = run;
      run += v;
    }
    CE[tid] = (float)run;  // ce[e]
  }
  __syncthreads();
  {  // per (e,seg): exclusive scan within segment
    int run = SEG[seg * NE + e];
    for (int c = seg * 32; c < seg * 32 + 32; ++c) {
      const int v = H[c * NE + e];
      H[c * NE + e] = run;
      run += v;
    }
  }
  if (tid < 64) {  // l_aux
    float p = (MEp[tid] + MEp[NE + tid] + MEp[2 * NE + tid] + MEp[3 * NE + tid])
              * CE[tid];
#pragma unroll
    for (int off = 32; off > 0; off >>= 1) p += __shfl_down(p, off);
    if (tid == 0) out[0] = p * ((float)NE / ((float)TOK * (float)TOK));
  }
  __syncthreads();
#pragma unroll 4
  for (int i = tid; i < TOK; i += 256) {  // locations1_s
    const int ex = idx_int[i];
    out[1 + TOK + i] = (float)(H[(i >> 6) * NE + ex] + rankp[i]);
  }
}

extern "C" void kernel_launch(void* const* d_in, const int* in_sizes, int n_in,
                              void* d_out, int out_size, void* d_ws, size_t ws_size,
                              hipStream_t stream) {
  const float* A = (const float*)d_in[0];   // [8192, 4096] fp32
  const float* W = (const float*)d_in[1];   // [64, 4096] fp32
  float* out = (float*)d_out;               // 1 + 8192*3 floats
  char* ws = (char*)d_ws;

  float* partial = (float*)ws;                                  // 16 MB
  size_t off = (size_t)KS * TOK * NE * sizeof(float);
  _Float16* whi = (_Float16*)(ws + off);  off += (size_t)4 * TOTKS * 64 * 16;  // 512 KB
  _Float16* wlo = (_Float16*)(ws + off);  off += (size_t)4 * TOTKS * 64 * 16;  // 512 KB
  float* me_part = (float*)(ws + off);  off += (size_t)NCH * NE * sizeof(float);
  int* idx_int = (int*)(ws + off);      off += (size_t)TOK * sizeof(int);
  int* rankp   = (int*)(ws + off);      off += (size_t)TOK * sizeof(int);
  int* hist    = (int*)(ws + off);

  hipLaunchKernelGGL(prepack_w, dim3(128), dim3(256), 0, stream, W,
                     (f16x8*)whi, (f16x8*)wlo);
  hipLaunchKernelGGL(gemm_split, dim3(NT * KS), dim3(512), 0, stream,
                     A, whi, wlo, partial);
  hipLaunchKernelGGL(gating, dim3(NCH), dim3(256), 0, stream, partial, out,
                     idx_int, rankp, hist, me_part);
  hipLaunchKernelGGL(finalize, dim3(1), dim3(256), 0, stream, idx_int, rankp,
                     hist, me_part, out);
}